// Round 7
// baseline (738.386 us; speedup 1.0000x reference)
//
#include <hip/hip_runtime.h>
#include <hip/hip_bf16.h>
#include <cstdint>
#include <cstddef>

#define N_TOK 65536
#define HIDDEN 768
#define NHEAD 12
#define HEADD 64

typedef __bf16 bf16x8 __attribute__((ext_vector_type(8)));
typedef float f32x4 __attribute__((ext_vector_type(4)));

__device__ __forceinline__ float bflo(unsigned int u) {
  return __builtin_bit_cast(float, (unsigned int)(u << 16));
}
__device__ __forceinline__ float bfhi(unsigned int u) {
  return __builtin_bit_cast(float, (unsigned int)(u & 0xffff0000u));
}
__device__ __forceinline__ unsigned short f2bf(float f) {
  unsigned int x = __builtin_bit_cast(unsigned int, f);
  unsigned int r = x + 0x7fffu + ((x >> 16) & 1u);  // RTNE
  return (unsigned short)(r >> 16);
}

__device__ __forceinline__ void gload_lds16(const void* g, void* l) {
  __builtin_amdgcn_global_load_lds(
      (const __attribute__((address_space(1))) void*)g,
      (__attribute__((address_space(3))) void*)l, 16, 0, 0);
}

// Full bank swizzle: physical = logical ^ ((row&7)<<4).  (verified: 0 conflicts)
__device__ __forceinline__ bf16x8 ldsfrag(const char* base, int row, int kb) {
  int L = (row << 7) + kb;        // 128 B rows
  L ^= (row & 7) << 4;
  return *(const bf16x8*)(base + L);
}

// ---------------- f32 -> bf16 convert of x (vectorized) ----------------
__global__ void cvt_kernel(const float* __restrict__ in,
                           unsigned short* __restrict__ out, int n4) {
  int i = blockIdx.x * blockDim.x + threadIdx.x;
  if (i >= n4) return;
  float4 v = ((const float4*)in)[i];
  ushort4 o;
  o.x = f2bf(v.x); o.y = f2bf(v.y); o.z = f2bf(v.z); o.w = f2bf(v.w);
  ((ushort4*)out)[i] = o;
}

// ------- fused weight converts + bias concat (one launch) -------
__global__ void cvtw_kernel(const float* __restrict__ Wq, const float* __restrict__ Wk,
                            const float* __restrict__ Wv, const float* __restrict__ Wo,
                            const float* __restrict__ bq, const float* __restrict__ bk,
                            const float* __restrict__ bv,
                            unsigned short* __restrict__ wqkv,
                            unsigned short* __restrict__ wo_bf,
                            float* __restrict__ bqkv) {
  const int bid = blockIdx.x;
  if (bid < 2304) {
    const int mat = bid / 576;
    const int idx = (bid - mat * 576) * 256 + threadIdx.x;
    const float* src = mat == 0 ? Wq : mat == 1 ? Wk : mat == 2 ? Wv : Wo;
    unsigned short* dst = (mat == 3) ? wo_bf : wqkv + mat * (HIDDEN * HIDDEN);
    float4 v = ((const float4*)src)[idx];
    ushort4 o;
    o.x = f2bf(v.x); o.y = f2bf(v.y); o.z = f2bf(v.z); o.w = f2bf(v.w);
    ((ushort4*)dst)[idx] = o;
  } else {
    const int i = (bid - 2304) * 256 + threadIdx.x;
    if (i < 576) {
      const float* src = i < 192 ? bq : i < 384 ? bk : bv;
      const int off = i < 192 ? i : i < 384 ? i - 192 : i - 384;
      ((float4*)bqkv)[i] = ((const float4*)src)[off];
    }
  }
}

// ---------- fragment read / mfma helpers (16x16x32) ----------
__device__ __forceinline__ void rdA(const char* la, int rowbase, int kpart,
                                    bf16x8* dst) {
#pragma unroll
  for (int m = 0; m < 4; ++m)
#pragma unroll
    for (int kk = 0; kk < 2; ++kk)
      dst[m * 2 + kk] = ldsfrag(la, rowbase + m * 16, kk * 64 + kpart);
}
__device__ __forceinline__ void rdB(const char* lb, int rowbase, int kpart,
                                    bf16x8* dst) {
#pragma unroll
  for (int n = 0; n < 2; ++n)
#pragma unroll
    for (int kk = 0; kk < 2; ++kk)
      dst[n * 2 + kk] = ldsfrag(lb, rowbase + n * 16, kk * 64 + kpart);
}
__device__ __forceinline__ void mfma16(const bf16x8* a, const bf16x8* b,
                                       f32x4 acc[8][4], int mb, int nb) {
#pragma unroll
  for (int m = 0; m < 4; ++m)
#pragma unroll
    for (int n = 0; n < 2; ++n)
#pragma unroll
      for (int kk = 0; kk < 2; ++kk)
        acc[mb + m][nb + n] = __builtin_amdgcn_mfma_f32_16x16x32_bf16(
            a[m * 2 + kk], b[n * 2 + kk], acc[mb + m][nb + n], 0, 0, 0);
}

// ------------- 256x256 bf16 GEMM, C = A @ B^T + bias -------------
// Faithful m201-style 8-phase schedule: 8 phases per TWO K-tiles (BK=64),
// 2-deep K-tile LDS ring (tile t in buf[t&1], bases compile-time),
// one half-tile stage (2 x global_load_lds) per phase, 2 barriers/phase,
// lgkmcnt(8) on 12-read phases, counted vmcnt(4) at phases 4 & 8 only.
// 512 thr = 8 waves (2M x 4N), per-wave 128x64, 16x16x32 MFMA,
// (row&7)<<4 XOR swizzle (0 conflicts, verified).
template <int F32OUT>
__global__ __launch_bounds__(512, 2)
void gemm256(const unsigned short* __restrict__ A,
             const unsigned short* __restrict__ B,
             const float* __restrict__ bias,
             void* __restrict__ C, int K, int NBLK, int ldc) {
  __shared__ __align__(16) char lds[131072];
  const int tid = threadIdx.x;
  const int lane = tid & 63;
  const int wave = tid >> 6;
  const int wr = wave >> 2;   // 0..1
  const int wc = wave & 3;    // 0..3

  // XCD-aware bijective swizzle (grid % 8 == 0 by construction)
  const int nwg = gridDim.x;
  const int bid = blockIdx.x;
  const int wg = (bid & 7) * (nwg >> 3) + (bid >> 3);
  const int mb = wg / NBLK;
  const int nb = wg - mb * NBLK;
  const int brow = mb << 8;
  const int bcol = nb << 8;

  // staging: linear LDS dest (tid*16), inverse-swizzled global source
  const int Ld = tid * 16;
  const int Ls = Ld ^ (((tid >> 3) & 7) << 4);
  const int sr = Ls >> 7;
  const int sc = (Ls & 127) >> 1;

  const int NT = K >> 6;   // 12
  const int NI = NT >> 1;  // 6

  const unsigned short* Asrc = A + (size_t)(brow + sr) * K + sc;
  const unsigned short* Bsrc = B + (size_t)(bcol + sr) * K + sc;

  // one half-tile = 2 loads. bufbase/matoff compile-time at call sites.
#define STG(Src, bufbase, matoff, half, kt)                       \
  do {                                                            \
    const unsigned short* _s = (Src) + ((half) * 128) * K + (kt) * 64; \
    char* _d = (char*)lds + (bufbase) + (matoff) + ((half) << 14) + Ld; \
    gload_lds16(_s, _d);                                          \
    gload_lds16(_s + 64 * K, _d + 8192);                          \
  } while (0)

#define PH_TAIL(MFMA_STMT)                                        \
  do {                                                            \
    __builtin_amdgcn_s_barrier();                                 \
    asm volatile("s_waitcnt lgkmcnt(0)" ::: "memory");            \
    __builtin_amdgcn_s_setprio(1);                                \
    MFMA_STMT;                                                    \
    __builtin_amdgcn_s_setprio(0);                                \
    __builtin_amdgcn_s_barrier();                                 \
  } while (0)

  f32x4 acc[8][4];
#pragma unroll
  for (int m = 0; m < 8; ++m)
#pragma unroll
    for (int n = 0; n < 4; ++n) acc[m][n] = (f32x4){0.f, 0.f, 0.f, 0.f};

  const int arow = wr * 128 + (lane & 15);
  const int nrow = wc * 64 + (lane & 15);
  const int kpart = (lane >> 4) * 16;

  // buf0 = tiles even, buf1 = tiles odd (2-deep ring, constant bases)
  const char* la0 = lds;
  const char* lb0 = lds + 32768;
  const char* la1 = lds + 65536;
  const char* lb1 = lds + 98304;

  // ---- prologue: stage A(0),B(0),A(1) (12 loads); wait A0,B0; barrier ----
  STG(Asrc, 0, 0, 0, 0);
  STG(Asrc, 0, 0, 1, 0);
  STG(Bsrc, 0, 32768, 0, 0);
  STG(Bsrc, 0, 32768, 1, 0);
  STG(Asrc, 65536, 0, 0, 1);
  STG(Asrc, 65536, 0, 1, 1);
  asm volatile("s_waitcnt vmcnt(4)" ::: "memory");
  __builtin_amdgcn_s_barrier();

  for (int i = 0; i < NI; ++i) {
    const int t2 = 2 * i;        // read phases 1-4 (buf0)
    const int t3 = 2 * i + 1;    // read phases 5-8 (buf1)
    const bool s34 = (t2 + 2 < NT);   // stage A(t2+2) -> buf0
    const bool s56 = (t2 + 2 < NT);   // stage B(t2+2) -> buf0
    const bool s78 = (t3 + 2 < NT);   // stage A(t3+2) -> buf1

    bf16x8 aLo[8], aHi[8], bLo[4], bHi[4];

    // ---- PH1: read aLo+bLo(t2) [12]; stage B(t3) h0; lgkm(8); Q(0,0) ----
    rdA(la0, arow, kpart, aLo);
    rdB(lb0, nrow, kpart, bLo);
    STG(Bsrc, 65536, 32768, 0, t3);
    asm volatile("s_waitcnt lgkmcnt(8)" ::: "memory");
    PH_TAIL(mfma16(aLo, bLo, acc, 0, 0));

    // ---- PH2: read aHi(t2) [8]; stage B(t3) h1; Q(1,0) ----
    rdA(la0, arow + 64, kpart, aHi);
    STG(Bsrc, 65536, 32768, 1, t3);
    PH_TAIL(mfma16(aHi, bLo, acc, 4, 0));

    // ---- PH3: read bHi(t2) [4]; stage A(t2+2) h0; Q(1,1) ----
    rdB(lb0, nrow + 32, kpart, bHi);
    if (s34) STG(Asrc, 0, 0, 0, t2 + 2);
    PH_TAIL(mfma16(aHi, bHi, acc, 4, 2));

    // ---- PH4: stage A(t2+2) h1; vmcnt(4); Q(0,1) ----
    if (s34) {
      STG(Asrc, 0, 0, 1, t2 + 2);
      asm volatile("s_waitcnt vmcnt(4)" ::: "memory");
    } else {
      asm volatile("s_waitcnt vmcnt(0)" ::: "memory");
    }
    PH_TAIL(mfma16(aLo, bHi, acc, 0, 2));

    // ---- PH5: read aLo+bLo(t3) [12]; stage B(t2+2) h0; lgkm(8); Q(0,0) ----
    rdA(la1, arow, kpart, aLo);
    rdB(lb1, nrow, kpart, bLo);
    if (s56) STG(Bsrc, 0, 32768, 0, t2 + 2);
    asm volatile("s_waitcnt lgkmcnt(8)" ::: "memory");
    PH_TAIL(mfma16(aLo, bLo, acc, 0, 0));

    // ---- PH6: read aHi(t3) [8]; stage B(t2+2) h1; Q(1,0) ----
    rdA(la1, arow + 64, kpart, aHi);
    if (s56) STG(Bsrc, 0, 32768, 1, t2 + 2);
    PH_TAIL(mfma16(aHi, bLo, acc, 4, 0));

    // ---- PH7: read bHi(t3) [4]; stage A(t3+2) h0; Q(1,1) ----
    rdB(lb1, nrow + 32, kpart, bHi);
    if (s78) STG(Asrc, 65536, 0, 0, t3 + 2);
    PH_TAIL(mfma16(aHi, bHi, acc, 4, 2));

    // ---- PH8: stage A(t3+2) h1; vmcnt(4); Q(0,1) ----
    if (s78) {
      STG(Asrc, 65536, 0, 1, t3 + 2);
      asm volatile("s_waitcnt vmcnt(4)" ::: "memory");
    } else {
      asm volatile("s_waitcnt vmcnt(0)" ::: "memory");
    }
    PH_TAIL(mfma16(aLo, bHi, acc, 0, 2));
  }
#undef STG
#undef PH_TAIL

  // ---------------- epilogue ----------------
  const int crow0 = brow + wr * 128 + (lane >> 4) * 4;
  const int ccol0 = bcol + wc * 64 + (lane & 15);
#pragma unroll
  for (int m = 0; m < 8; ++m) {
#pragma unroll
    for (int n = 0; n < 4; ++n) {
      const int col = ccol0 + n * 16;
      const float bv = bias[col];
#pragma unroll
      for (int r = 0; r < 4; ++r) {
        const int row = crow0 + m * 16 + r;
        const float v = acc[m][n][r] + bv;
        if (F32OUT)
          ((float*)C)[(size_t)row * ldc + col] = v;
        else
          ((unsigned short*)C)[(size_t)row * ldc + col] = f2bf(v);
      }
    }
  }
}

// ---------------- per-token 12x12 attention -----------------------
__global__ void attn_kernel(const unsigned short* __restrict__ qkv,
                            unsigned short* __restrict__ ctx) {
  const int gtid = blockIdx.x * blockDim.x + threadIdx.x;
  const int t = gtid / 12;
  const int h = gtid - t * 12;
  if (t >= N_TOK) return;

  const unsigned short* row = qkv + (size_t)t * 2304;
  const unsigned short* qp = row + h * 64;
  const unsigned short* kp = row + 768;

  float s[12];
#pragma unroll
  for (int g = 0; g < 12; ++g) s[g] = 0.f;

  for (int c = 0; c < 8; ++c) {
    const uint4 qc = *(const uint4*)(qp + c * 8);
    const unsigned int qw[4] = {qc.x, qc.y, qc.z, qc.w};
#pragma unroll
    for (int j = 0; j < 8; ++j) {
      const float qd = (j & 1) ? bfhi(qw[j >> 1]) : bflo(qw[j >> 1]);
      const unsigned short* kd = kp + (c * 8 + j) * 12;
      const uint2 k0 = *(const uint2*)(kd);
      const uint2 k1 = *(const uint2*)(kd + 4);
      const uint2 k2 = *(const uint2*)(kd + 8);
      s[0] += qd * bflo(k0.x);  s[1] += qd * bfhi(k0.x);
      s[2] += qd * bflo(k0.y);  s[3] += qd * bfhi(k0.y);
      s[4] += qd * bflo(k1.x);  s[5] += qd * bfhi(k1.x);
      s[6] += qd * bflo(k1.y);  s[7] += qd * bfhi(k1.y);
      s[8] += qd * bflo(k2.x);  s[9] += qd * bfhi(k2.x);
      s[10] += qd * bflo(k2.y); s[11] += qd * bfhi(k2.y);
    }
  }

  float mx = s[0];
#pragma unroll
  for (int g = 1; g < 12; ++g) mx = fmaxf(mx, s[g]);
  float p[12];
  float sum = 0.f;
#pragma unroll
  for (int g = 0; g < 12; ++g) {
    p[g] = __expf((s[g] - mx) * 0.125f);
    sum += p[g];
  }
  const float inv = 1.0f / sum;
#pragma unroll
  for (int g = 0; g < 12; ++g) p[g] *= inv;

  const unsigned short* vp = row + 1536;
  unsigned short* op = ctx + (size_t)t * 768 + h * 64;
  for (int c = 0; c < 8; ++c) {
    float o[8];
#pragma unroll
    for (int k = 0; k < 8; ++k) o[k] = 0.f;
#pragma unroll
    for (int g = 0; g < 12; ++g) {
      const uint4 vv = *(const uint4*)(vp + g * 64 + c * 8);
      const unsigned int vw[4] = {vv.x, vv.y, vv.z, vv.w};
#pragma unroll
      for (int k = 0; k < 4; ++k) {
        o[2 * k] += p[g] * bflo(vw[k]);
        o[2 * k + 1] += p[g] * bfhi(vw[k]);
      }
    }
    uint4 w;
    w.x = (unsigned int)f2bf(o[0]) | ((unsigned int)f2bf(o[1]) << 16);
    w.y = (unsigned int)f2bf(o[2]) | ((unsigned int)f2bf(o[3]) << 16);
    w.z = (unsigned int)f2bf(o[4]) | ((unsigned int)f2bf(o[5]) << 16);
    w.w = (unsigned int)f2bf(o[6]) | ((unsigned int)f2bf(o[7]) << 16);
    *(uint4*)(op + c * 8) = w;
  }
}

extern "C" void kernel_launch(void* const* d_in, const int* in_sizes, int n_in,
                              void* d_out, int out_size, void* d_ws, size_t ws_size,
                              hipStream_t stream) {
  const float* x = (const float*)d_in[0];
  const float* Wq = (const float*)d_in[1];
  const float* bq = (const float*)d_in[2];
  const float* Wk = (const float*)d_in[3];
  const float* bk = (const float*)d_in[4];
  const float* Wv = (const float*)d_in[5];
  const float* bv = (const float*)d_in[6];
  const float* Wo = (const float*)d_in[7];
  const float* bo = (const float*)d_in[8];
  float* out = (float*)d_out;

  char* ws = (char*)d_ws;
  unsigned short* x_bf = (unsigned short*)ws;
  unsigned short* ctx = (unsigned short*)ws;  // alias: x_bf dead before attn
  unsigned short* qkv = (unsigned short*)(ws + 100663296u);
  unsigned short* wqkv = (unsigned short*)(ws + 402653184u);
  unsigned short* wo_bf = (unsigned short*)(ws + 406192128u);
  float* bqkv = (float*)(ws + 407371776u);

  const int n4x = N_TOK * HIDDEN / 4;
  cvt_kernel<<<n4x / 256, 256, 0, stream>>>(x, x_bf, n4x);
  cvtw_kernel<<<2307, 256, 0, stream>>>(Wq, Wk, Wv, Wo, bq, bk, bv,
                                        wqkv, wo_bf, bqkv);

  // QKV GEMM: [65536 x 768] @ [2304 x 768]^T + bqkv -> qkv bf16
  gemm256<0><<<(N_TOK / 256) * (2304 / 256), 512, 0, stream>>>(
      x_bf, wqkv, bqkv, qkv, HIDDEN, 2304 / 256, 2304);

  // per-token attention -> ctx bf16
  attn_kernel<<<(N_TOK * NHEAD) / 256, 256, 0, stream>>>(qkv, ctx);

  // output projection: [65536 x 768] @ [768 x 768]^T + bo -> out f32
  gemm256<1><<<(N_TOK / 256) * (HIDDEN / 256), 512, 0, stream>>>(
      ctx, wo_bf, bo, out, HIDDEN, HIDDEN / 256, HIDDEN);
}

// Round 8
// 675.809 us; speedup vs baseline: 1.0926x; 1.0926x over previous
//
#include <hip/hip_runtime.h>
#include <hip/hip_bf16.h>
#include <cstdint>
#include <cstddef>

#define N_TOK 65536
#define HIDDEN 768
#define NHEAD 12
#define HEADD 64

typedef __bf16 bf16x8 __attribute__((ext_vector_type(8)));
typedef float f32x4 __attribute__((ext_vector_type(4)));

__device__ __forceinline__ float bflo(unsigned int u) {
  return __builtin_bit_cast(float, (unsigned int)(u << 16));
}
__device__ __forceinline__ float bfhi(unsigned int u) {
  return __builtin_bit_cast(float, (unsigned int)(u & 0xffff0000u));
}
__device__ __forceinline__ unsigned short f2bf(float f) {
  unsigned int x = __builtin_bit_cast(unsigned int, f);
  unsigned int r = x + 0x7fffu + ((x >> 16) & 1u);  // RTNE
  return (unsigned short)(r >> 16);
}

__device__ __forceinline__ void gload_lds16(const void* g, void* l) {
  __builtin_amdgcn_global_load_lds(
      (const __attribute__((address_space(1))) void*)g,
      (__attribute__((address_space(3))) void*)l, 16, 0, 0);
}

// Full bank swizzle: physical = logical ^ ((row&7)<<4).  (verified: 0 conflicts)
__device__ __forceinline__ bf16x8 ldsfrag(const char* base, int row, int kb) {
  int L = (row << 7) + kb;        // 128 B rows
  L ^= (row & 7) << 4;
  return *(const bf16x8*)(base + L);
}

// ------- ALL converts in one launch: x, 4 weights, bias concat -------
// blocks [0, 49152): x cvt (12582912 float4s)
// blocks [49152, 51456): weight cvt (576 blocks per matrix)
// blocks [51456, 51459): bias concat
__global__ void cvt_all_kernel(const float* __restrict__ x,
                               const float* __restrict__ Wq, const float* __restrict__ Wk,
                               const float* __restrict__ Wv, const float* __restrict__ Wo,
                               const float* __restrict__ bq, const float* __restrict__ bk,
                               const float* __restrict__ bv,
                               unsigned short* __restrict__ x_bf,
                               unsigned short* __restrict__ wqkv,
                               unsigned short* __restrict__ wo_bf,
                               float* __restrict__ bqkv) {
  const int bid = blockIdx.x;
  if (bid < 49152) {
    const int idx = bid * 256 + threadIdx.x;
    float4 v = ((const float4*)x)[idx];
    ushort4 o;
    o.x = f2bf(v.x); o.y = f2bf(v.y); o.z = f2bf(v.z); o.w = f2bf(v.w);
    ((ushort4*)x_bf)[idx] = o;
  } else if (bid < 51456) {
    const int wb = bid - 49152;
    const int mat = wb / 576;
    const int idx = (wb - mat * 576) * 256 + threadIdx.x;
    const float* src = mat == 0 ? Wq : mat == 1 ? Wk : mat == 2 ? Wv : Wo;
    unsigned short* dst = (mat == 3) ? wo_bf : wqkv + mat * (HIDDEN * HIDDEN);
    float4 v = ((const float4*)src)[idx];
    ushort4 o;
    o.x = f2bf(v.x); o.y = f2bf(v.y); o.z = f2bf(v.z); o.w = f2bf(v.w);
    ((ushort4*)dst)[idx] = o;
  } else {
    const int i = (bid - 51456) * 256 + threadIdx.x;
    if (i < 576) {
      const float* src = i < 192 ? bq : i < 384 ? bk : bv;
      const int off = i < 192 ? i : i < 384 ? i - 192 : i - 384;
      ((float4*)bqkv)[i] = ((const float4*)src)[off];
    }
  }
}

// ------------- 256x256 bf16 GEMM, C = A @ B^T + bias (R4 config) -------------
// BK=64, 512 thr = 8 waves (2M x 4N), per-wave 128x64, 16x16x32 MFMA,
// double-buffered LDS (128 KiB), XOR swizzle, single barrier per phase:
//   {reads; stage; [vmcnt]; s_barrier; lgkmcnt(0); setprio1; MFMA; setprio0}
template <int F32OUT>
__global__ __launch_bounds__(512, 2)
void gemm256(const unsigned short* __restrict__ A,
             const unsigned short* __restrict__ B,
             const float* __restrict__ bias,
             void* __restrict__ C, int K, int NBLK, int ldc) {
  __shared__ __align__(16) char lds[131072];
  const int tid = threadIdx.x;
  const int lane = tid & 63;
  const int wave = tid >> 6;
  const int wr = wave >> 2;   // 0..1
  const int wc = wave & 3;    // 0..3

  // XCD-aware bijective swizzle (grid % 8 == 0 by construction)
  const int nwg = gridDim.x;
  const int bid = blockIdx.x;
  const int wg = (bid & 7) * (nwg >> 3) + (bid >> 3);
  const int mb = wg / NBLK;
  const int nb = wg - mb * NBLK;
  const int brow = mb << 8;
  const int bcol = nb << 8;

  // staging: linear LDS dest (tid*16), inverse-swizzled global source
  const int Ld = tid * 16;
  const int Ls = Ld ^ (((tid >> 3) & 7) << 4);
  const int sr = Ls >> 7;           // source row within 64-row chunk
  const int sc = (Ls & 127) >> 1;   // source col element

  const int NT = K >> 6;

#define STAGE(Mat, panelRow, bufbase, matoff, half, kt)                         \
  do {                                                                          \
    const unsigned short* _s =                                                  \
        (Mat) + (size_t)((panelRow) + (half) * 128 + sr) * K + ((kt) << 6) + sc;\
    char* _d = (char*)lds + (bufbase) + (matoff) + ((half) << 14) + Ld;         \
    gload_lds16(_s, _d);                                                        \
    gload_lds16(_s + ((size_t)K << 6), _d + 8192);                              \
  } while (0)

  f32x4 acc[8][4];
#pragma unroll
  for (int m = 0; m < 8; ++m)
#pragma unroll
    for (int n = 0; n < 4; ++n) acc[m][n] = (f32x4){0.f, 0.f, 0.f, 0.f};

  const int arow = wr * 128 + (lane & 15);
  const int nrow = wc * 64 + (lane & 15);
  const int kpart = (lane >> 4) * 16;  // byte offset of this lane's k-slice

  // ---- prologue: stage tile 0 (A,B), drain, barrier ----
  STAGE(A, brow, 0, 0, 0, 0);
  STAGE(A, brow, 0, 0, 1, 0);
  STAGE(B, bcol, 0, 32768, 0, 0);
  STAGE(B, bcol, 0, 32768, 1, 0);
  asm volatile("s_waitcnt vmcnt(0)" ::: "memory");
  __builtin_amdgcn_s_barrier();

  for (int t = 0; t < NT; ++t) {
    const int cur = t & 1;
    const char* la = lds + cur * 65536;
    const char* lb = la + 32768;
    const int obuf = (cur ^ 1) * 65536;  // buffer for tile t+1

    bf16x8 aLo[8], aHi[8], bLo[4], bHi[4];

    // -------- PH1: read aLo(8)+bLo(4); stage A(t+1); MFMA Q(lo,lo) --------
#pragma unroll
    for (int m = 0; m < 4; ++m)
#pragma unroll
      for (int kk = 0; kk < 2; ++kk)
        aLo[m * 2 + kk] = ldsfrag(la, arow + m * 16, kk * 64 + kpart);
#pragma unroll
    for (int n = 0; n < 2; ++n)
#pragma unroll
      for (int kk = 0; kk < 2; ++kk)
        bLo[n * 2 + kk] = ldsfrag(lb, nrow + n * 16, kk * 64 + kpart);
    if (t + 1 < NT) {
      STAGE(A, brow, obuf, 0, 0, t + 1);
      STAGE(A, brow, obuf, 0, 1, t + 1);
    }
    __builtin_amdgcn_s_barrier();
    asm volatile("s_waitcnt lgkmcnt(0)" ::: "memory");
    __builtin_amdgcn_s_setprio(1);
#pragma unroll
    for (int m = 0; m < 4; ++m)
#pragma unroll
      for (int n = 0; n < 2; ++n)
#pragma unroll
        for (int kk = 0; kk < 2; ++kk)
          acc[m][n] = __builtin_amdgcn_mfma_f32_16x16x32_bf16(
              aLo[m * 2 + kk], bLo[n * 2 + kk], acc[m][n], 0, 0, 0);
    __builtin_amdgcn_s_setprio(0);

    // -------- PH2: read aHi(8); stage B(t+1); MFMA Q(hi,lo) --------
#pragma unroll
    for (int m = 0; m < 4; ++m)
#pragma unroll
      for (int kk = 0; kk < 2; ++kk)
        aHi[m * 2 + kk] = ldsfrag(la, arow + 64 + m * 16, kk * 64 + kpart);
    if (t + 1 < NT) {
      STAGE(B, bcol, obuf, 32768, 0, t + 1);
      STAGE(B, bcol, obuf, 32768, 1, t + 1);
    }
    __builtin_amdgcn_s_barrier();
    asm volatile("s_waitcnt lgkmcnt(0)" ::: "memory");
    __builtin_amdgcn_s_setprio(1);
#pragma unroll
    for (int m = 0; m < 4; ++m)
#pragma unroll
      for (int n = 0; n < 2; ++n)
#pragma unroll
        for (int kk = 0; kk < 2; ++kk)
          acc[4 + m][n] = __builtin_amdgcn_mfma_f32_16x16x32_bf16(
              aHi[m * 2 + kk], bLo[n * 2 + kk], acc[4 + m][n], 0, 0, 0);
    __builtin_amdgcn_s_setprio(0);

    // -------- PH3: read bHi(4); MFMA Q(hi,hi) --------
#pragma unroll
    for (int n = 0; n < 2; ++n)
#pragma unroll
      for (int kk = 0; kk < 2; ++kk)
        bHi[n * 2 + kk] = ldsfrag(lb, nrow + 32 + n * 16, kk * 64 + kpart);
    __builtin_amdgcn_s_barrier();
    asm volatile("s_waitcnt lgkmcnt(0)" ::: "memory");
    __builtin_amdgcn_s_setprio(1);
#pragma unroll
    for (int m = 0; m < 4; ++m)
#pragma unroll
      for (int n = 0; n < 2; ++n)
#pragma unroll
        for (int kk = 0; kk < 2; ++kk)
          acc[4 + m][n + 2] = __builtin_amdgcn_mfma_f32_16x16x32_bf16(
              aHi[m * 2 + kk], bHi[n * 2 + kk], acc[4 + m][n + 2], 0, 0, 0);
    __builtin_amdgcn_s_setprio(0);

    // -------- PH4: vmcnt drain (t+1 staged >=2 phases ago); MFMA Q(lo,hi) --
    asm volatile("s_waitcnt vmcnt(0)" ::: "memory");
    __builtin_amdgcn_s_barrier();
    __builtin_amdgcn_s_setprio(1);
#pragma unroll
    for (int m = 0; m < 4; ++m)
#pragma unroll
      for (int n = 0; n < 2; ++n)
#pragma unroll
        for (int kk = 0; kk < 2; ++kk)
          acc[m][n + 2] = __builtin_amdgcn_mfma_f32_16x16x32_bf16(
              aLo[m * 2 + kk], bHi[n * 2 + kk], acc[m][n + 2], 0, 0, 0);
    __builtin_amdgcn_s_setprio(0);
  }
#undef STAGE

  // ---------------- epilogue ----------------
  const int crow0 = brow + wr * 128 + (lane >> 4) * 4;
  const int ccol0 = bcol + wc * 64 + (lane & 15);
#pragma unroll
  for (int m = 0; m < 8; ++m) {
#pragma unroll
    for (int n = 0; n < 4; ++n) {
      const int col = ccol0 + n * 16;
      const float bv = bias[col];
#pragma unroll
      for (int r = 0; r < 4; ++r) {
        const int row = crow0 + m * 16 + r;
        const float v = acc[m][n][r] + bv;
        if (F32OUT)
          ((float*)C)[(size_t)row * ldc + col] = v;
        else
          ((unsigned short*)C)[(size_t)row * ldc + col] = f2bf(v);
      }
    }
  }
}

// ---------------- per-token 12x12 attention -----------------------
__global__ void attn_kernel(const unsigned short* __restrict__ qkv,
                            unsigned short* __restrict__ ctx) {
  const int gtid = blockIdx.x * blockDim.x + threadIdx.x;
  const int t = gtid / 12;
  const int h = gtid - t * 12;
  if (t >= N_TOK) return;

  const unsigned short* row = qkv + (size_t)t * 2304;
  const unsigned short* qp = row + h * 64;
  const unsigned short* kp = row + 768;

  float s[12];
#pragma unroll
  for (int g = 0; g < 12; ++g) s[g] = 0.f;

  for (int c = 0; c < 8; ++c) {
    const uint4 qc = *(const uint4*)(qp + c * 8);
    const unsigned int qw[4] = {qc.x, qc.y, qc.z, qc.w};
#pragma unroll
    for (int j = 0; j < 8; ++j) {
      const float qd = (j & 1) ? bfhi(qw[j >> 1]) : bflo(qw[j >> 1]);
      const unsigned short* kd = kp + (c * 8 + j) * 12;
      const uint2 k0 = *(const uint2*)(kd);
      const uint2 k1 = *(const uint2*)(kd + 4);
      const uint2 k2 = *(const uint2*)(kd + 8);
      s[0] += qd * bflo(k0.x);  s[1] += qd * bfhi(k0.x);
      s[2] += qd * bflo(k0.y);  s[3] += qd * bfhi(k0.y);
      s[4] += qd * bflo(k1.x);  s[5] += qd * bfhi(k1.x);
      s[6] += qd * bflo(k1.y);  s[7] += qd * bfhi(k1.y);
      s[8] += qd * bflo(k2.x);  s[9] += qd * bfhi(k2.x);
      s[10] += qd * bflo(k2.y); s[11] += qd * bfhi(k2.y);
    }
  }

  float mx = s[0];
#pragma unroll
  for (int g = 1; g < 12; ++g) mx = fmaxf(mx, s[g]);
  float p[12];
  float sum = 0.f;
#pragma unroll
  for (int g = 0; g < 12; ++g) {
    p[g] = __expf((s[g] - mx) * 0.125f);
    sum += p[g];
  }
  const float inv = 1.0f / sum;
#pragma unroll
  for (int g = 0; g < 12; ++g) p[g] *= inv;

  const unsigned short* vp = row + 1536;
  unsigned short* op = ctx + (size_t)t * 768 + h * 64;
  for (int c = 0; c < 8; ++c) {
    float o[8];
#pragma unroll
    for (int k = 0; k < 8; ++k) o[k] = 0.f;
#pragma unroll
    for (int g = 0; g < 12; ++g) {
      const uint4 vv = *(const uint4*)(vp + g * 64 + c * 8);
      const unsigned int vw[4] = {vv.x, vv.y, vv.z, vv.w};
#pragma unroll
      for (int k = 0; k < 4; ++k) {
        o[2 * k] += p[g] * bflo(vw[k]);
        o[2 * k + 1] += p[g] * bfhi(vw[k]);
      }
    }
    uint4 w;
    w.x = (unsigned int)f2bf(o[0]) | ((unsigned int)f2bf(o[1]) << 16);
    w.y = (unsigned int)f2bf(o[2]) | ((unsigned int)f2bf(o[3]) << 16);
    w.z = (unsigned int)f2bf(o[4]) | ((unsigned int)f2bf(o[5]) << 16);
    w.w = (unsigned int)f2bf(o[6]) | ((unsigned int)f2bf(o[7]) << 16);
    *(uint4*)(op + c * 8) = w;
  }
}

extern "C" void kernel_launch(void* const* d_in, const int* in_sizes, int n_in,
                              void* d_out, int out_size, void* d_ws, size_t ws_size,
                              hipStream_t stream) {
  const float* x = (const float*)d_in[0];
  const float* Wq = (const float*)d_in[1];
  const float* bq = (const float*)d_in[2];
  const float* Wk = (const float*)d_in[3];
  const float* bk = (const float*)d_in[4];
  const float* Wv = (const float*)d_in[5];
  const float* bv = (const float*)d_in[6];
  const float* Wo = (const float*)d_in[7];
  const float* bo = (const float*)d_in[8];
  float* out = (float*)d_out;

  char* ws = (char*)d_ws;
  unsigned short* x_bf = (unsigned short*)ws;
  unsigned short* ctx = (unsigned short*)ws;  // alias: x_bf dead before attn
  unsigned short* qkv = (unsigned short*)(ws + 100663296u);
  unsigned short* wqkv = (unsigned short*)(ws + 402653184u);
  unsigned short* wo_bf = (unsigned short*)(ws + 406192128u);
  float* bqkv = (float*)(ws + 407371776u);

  // single fused convert kernel (x, weights, biases)
  cvt_all_kernel<<<51459, 256, 0, stream>>>(x, Wq, Wk, Wv, Wo, bq, bk, bv,
                                            x_bf, wqkv, wo_bf, bqkv);

  // QKV GEMM: [65536 x 768] @ [2304 x 768]^T + bqkv -> qkv bf16
  gemm256<0><<<(N_TOK / 256) * (2304 / 256), 512, 0, stream>>>(
      x_bf, wqkv, bqkv, qkv, HIDDEN, 2304 / 256, 2304);

  // per-token attention -> ctx bf16
  attn_kernel<<<(N_TOK * NHEAD) / 256, 256, 0, stream>>>(qkv, ctx);

  // output projection: [65536 x 768] @ [768 x 768]^T + bo -> out f32
  gemm256<1><<<(N_TOK / 256) * (HIDDEN / 256), 512, 0, stream>>>(
      ctx, wo_bf, bo, out, HIDDEN, HIDDEN / 256, HIDDEN);
}